// Round 1
// baseline (247.908 us; speedup 1.0000x reference)
//
#include <hip/hip_runtime.h>

// ClusterDiceLoss: segmented dice over 64 clusters of a 256^3 volume.
// Memory-bound: 201 MB read -> target ~35 us at ~6 TB/s.

#define NSEG 65          // clusters 0..64 (0 = background, dropped)
#define NWAVES 4         // 256 threads / wave64
#define BLOCKS 2048
#define THREADS 256

// Pack per-element contribution into one u64: inter<<42 | sum_p<<21 | sum_t.
// Per-block element count is ~8192 << 2^21, so fields never carry.
__device__ __forceinline__ unsigned long long pack_contrib(float p, float t) {
    unsigned long long sp = (p != 0.0f) ? 1ull : 0ull;
    unsigned long long st = (t != 0.0f) ? 1ull : 0ull;
    unsigned long long in = sp & st;
    return (in << 42) | (sp << 21) | st;
}

__global__ __launch_bounds__(THREADS) void seg_count_kernel(
    const float* __restrict__ pred,
    const float* __restrict__ target,
    const int* __restrict__ labels,
    unsigned int* __restrict__ g_counts,   // [3][NSEG] in d_ws, pre-zeroed
    int n)
{
    __shared__ unsigned long long s_cnt[NWAVES][NSEG];
    const int tid = threadIdx.x;
    const int wave = tid >> 6;

    // zero LDS counters
    for (int i = tid; i < NWAVES * NSEG; i += THREADS)
        ((unsigned long long*)s_cnt)[i] = 0ull;
    __syncthreads();

    const int n_vec = n >> 2;  // float4 groups
    const float4* __restrict__ p4 = (const float4*)pred;
    const float4* __restrict__ t4 = (const float4*)target;
    const int4*   __restrict__ l4 = (const int4*)labels;

    const int stride = gridDim.x * blockDim.x;
    for (int idx = blockIdx.x * blockDim.x + tid; idx < n_vec; idx += stride) {
        float4 p = p4[idx];
        float4 t = t4[idx];
        int4   l = l4[idx];
        atomicAdd(&s_cnt[wave][l.x], pack_contrib(p.x, t.x));
        atomicAdd(&s_cnt[wave][l.y], pack_contrib(p.y, t.y));
        atomicAdd(&s_cnt[wave][l.z], pack_contrib(p.z, t.z));
        atomicAdd(&s_cnt[wave][l.w], pack_contrib(p.w, t.w));
    }

    // scalar tail (n not divisible by 4), handled by block 0 only
    if (blockIdx.x == 0) {
        for (int idx = (n_vec << 2) + tid; idx < n; idx += THREADS) {
            atomicAdd(&s_cnt[wave][labels[idx]], pack_contrib(pred[idx], target[idx]));
        }
    }
    __syncthreads();

    // fold wave copies, unpack, one global atomic per (field, segment)
    for (int s = tid; s < NSEG; s += THREADS) {
        unsigned long long tot = 0;
        #pragma unroll
        for (int w = 0; w < NWAVES; ++w) tot += s_cnt[w][s];
        unsigned int in = (unsigned int)(tot >> 42);
        unsigned int sp = (unsigned int)((tot >> 21) & 0x1FFFFFu);
        unsigned int st = (unsigned int)(tot & 0x1FFFFFu);
        if (in) atomicAdd(&g_counts[s], in);
        if (sp) atomicAdd(&g_counts[NSEG + s], sp);
        if (st) atomicAdd(&g_counts[2 * NSEG + s], st);
    }
}

__global__ __launch_bounds__(64) void dice_finalize_kernel(
    const unsigned int* __restrict__ g_counts,
    const int* __restrict__ nc_ptr,
    float* __restrict__ out)
{
    const int nc = *nc_ptr;          // 64
    const int tid = threadIdx.x;
    float local = 0.0f;
    for (int c = 1 + tid; c <= nc; c += 64) {
        float in = (float)g_counts[c];
        float sp = (float)g_counts[NSEG + c];
        float st = (float)g_counts[2 * NSEG + c];
        float uni = sp + st;
        float dice = (uni > 0.0f) ? (2.0f * in / fmaxf(uni, 1.0f)) : 1.0f;
        local += dice;
    }
    // one-wave butterfly reduction over 64 lanes
    #pragma unroll
    for (int off = 32; off > 0; off >>= 1)
        local += __shfl_down(local, off);
    if (tid == 0) out[0] = 1.0f - local / (float)nc;
}

extern "C" void kernel_launch(void* const* d_in, const int* in_sizes, int n_in,
                              void* d_out, int out_size, void* d_ws, size_t ws_size,
                              hipStream_t stream) {
    const float* pred   = (const float*)d_in[0];
    const float* target = (const float*)d_in[1];
    const int*   labels = (const int*)d_in[2];
    const int*   nc_ptr = (const int*)d_in[3];
    float* out = (float*)d_out;
    unsigned int* g_counts = (unsigned int*)d_ws;

    const int n = in_sizes[0];

    // zero the 3*NSEG counter region (d_ws is poisoned to 0xAA each replay)
    hipMemsetAsync(d_ws, 0, 3 * NSEG * sizeof(unsigned int), stream);

    seg_count_kernel<<<BLOCKS, THREADS, 0, stream>>>(pred, target, labels, g_counts, n);
    dice_finalize_kernel<<<1, 64, 0, stream>>>(g_counts, nc_ptr, out);
}